// Round 8
// baseline (96.771 us; speedup 1.0000x reference)
//
#include <hip/hip_runtime.h>
#include <hip/hip_bf16.h>

#define DEV __device__ __forceinline__

typedef __bf16 bf16_t;
typedef bf16_t bf16x8 __attribute__((ext_vector_type(8)));
typedef float f32x4 __attribute__((ext_vector_type(4)));
typedef float f32x16 __attribute__((ext_vector_type(16)));
typedef unsigned int u32x4 __attribute__((ext_vector_type(4)));

constexpr int Bc = 2, Lc = 2048, Dc = 768, Hc = 12, HDc = 64;
constexpr int NTOK = Bc * Lc;     // 4096
constexpr int QKVN = 3 * Dc;      // 2304
constexpr float ATT_SCALE = 0.125f;          // 64^-0.5
constexpr float LOG2E = 1.44269504088896f;

DEV unsigned short f2bf(float f) {
  unsigned int u = __builtin_bit_cast(unsigned int, f);
  u += 0x7FFFu + ((u >> 16) & 1u);   // round-to-nearest-even
  return (unsigned short)(u >> 16);
}

DEV bf16x8 ld16(const unsigned short* p) {
  return __builtin_bit_cast(bf16x8, *reinterpret_cast<const u32x4*>(p));
}

DEV unsigned cvtpk(float lo, float hi) {
  unsigned r;
  asm("v_cvt_pk_bf16_f32 %0, %1, %2" : "=v"(r) : "v"(lo), "v"(hi));
  return r;
}

// async global->LDS, 16B per lane; lds dest = wave-uniform base + lane*16 (HW);
// global src address is PER-LANE (m173).
DEV void gload16(const unsigned short* g, unsigned short* l) {
  __builtin_amdgcn_global_load_lds(
      (const __attribute__((address_space(1))) unsigned int*)g,
      (__attribute__((address_space(3))) unsigned int*)l, 16, 0, 0);
}

// ---------------- fused prep: 3 bf16 converts + mask aux in ONE launch ----------------
// blocks [0,3072): x  [3072,4800): Wqkv  [4800,5376): Wout  [5376,5392): mask
__global__ __launch_bounds__(256) void prep_kernel(
    const float* __restrict__ x, const float* __restrict__ Wqkv,
    const float* __restrict__ Wout, const int* __restrict__ mask,
    unsigned short* __restrict__ xb, unsigned short* __restrict__ wqkvb,
    unsigned short* __restrict__ woutb, float* __restrict__ mb,
    int* __restrict__ mflag) {
  const int bid = blockIdx.x, tid = threadIdx.x;
  const float* src; unsigned short* dst; int base;
  if (bid < 3072)      { src = x;    dst = xb;    base = bid; }
  else if (bid < 4800) { src = Wqkv; dst = wqkvb; base = bid - 3072; }
  else if (bid < 5376) { src = Wout; dst = woutb; base = bid - 4800; }
  else {
    int i = (bid - 5376) * 256 + tid;
    int mv = mask[i];
    mb[i] = mv ? 0.f : -1e30f;
    unsigned long long anyz = __ballot(mv == 0);
    if ((tid & 63) == 0) mflag[i >> 6] = (anyz != 0ull) ? 1 : 0;
    return;
  }
  int i = (base * 256 + tid) * 4;
  float4 v = *reinterpret_cast<const float4*>(src + i);
  ushort4 o;
  o.x = f2bf(v.x); o.y = f2bf(v.y); o.z = f2bf(v.z); o.w = f2bf(v.w);
  *reinterpret_cast<ushort4*>(dst + i) = o;
}

// ---------------- bf16 GEMM, C[m,n] = sum_k A[m,k]*B[n,k] + bias[n] --------
// R16 (grid balance): MODE 0: BM=128,BN=96 -> grid 32x24=768 = exactly 3 blocks/CU
// (old 576 @ residency 3 -> CUs carried 2 or 3 -> 75% util). MODE 1: BM=64,BN=96 ->
// grid 64x8=512 = exactly 2/CU, 8 waves/CU (old 192 blocks left 64 CUs idle).
// BN=96: 96|768 so no tile crosses a q/k/v third; 16-col frags never cross a 64-col
// head boundary (frag col starts are multiples of 16 and 16|64).
// XCD swizzle (bijective, nwg%8==0) with col-major tile order: each XCD's 96 (resp 64)
// blocks share 3 (resp 1) B-column-tiles -> B slice resident in that XCD's L2.
// MODE 0 epilogue: scatter to q/k/vT bf16 buffers (Q pre-scaled); Q/K via per-wave LDS
// patch -> 16B vector stores.  MODE 1: write f32 Y.
template <int MODE>
__global__ __launch_bounds__(256) void gemm_bt(
    const unsigned short* __restrict__ A,   // [M][K] bf16
    const unsigned short* __restrict__ Bw,  // [N][K] bf16
    const float* __restrict__ bias,         // [N]
    unsigned short* __restrict__ qb, unsigned short* __restrict__ kb,
    unsigned short* __restrict__ vtb,
    float* __restrict__ Y,
    int M, int N, int K) {
  constexpr int BM = (MODE == 0) ? 128 : 64;
  constexpr int BN = 96, BK = 64;
  constexpr int AI = BM * BK / 2048;        // A gload iters: 4 / 2
  constexpr int MR = BM / 32;               // m frags per wave: 4 / 2
  __shared__ alignas(16) unsigned short a_lds[BM * BK];  // linear [row][64]
  __shared__ alignas(16) unsigned short b_lds[BN * BK];
  __shared__ alignas(16) unsigned short qk_patch[(MODE == 0) ? 4 : 1][16][56];

  const int tid = threadIdx.x;
  const int lane = tid & 63;
  const int l15 = lane & 15, lg = lane >> 4;
  const int wave = tid >> 6;
  const int wr = wave >> 1, wc = wave & 1;

  const int nm = M / BM;
  const int nwg = nm * (N / BN);
  // bijective XCD swizzle (nwg % 8 == 0), then col-major tile order
  const int t = (blockIdx.x & 7) * (nwg >> 3) + (blockIdx.x >> 3);
  const int m0 = (t % nm) * BM;
  const int n0 = (t / nm) * BN;

  f32x4 acc[MR][3] = {};

  for (int k0 = 0; k0 < K; k0 += BK) {
#pragma unroll
    for (int i = 0; i < AI; ++i) {
      int cc = i * 256 + tid;            // this thread's A chunk
      int row = cc >> 3, col = (cc & 7) * 8;
      gload16(A + (size_t)(m0 + row) * K + k0 + col, &a_lds[(i * 256 + wave * 64) * 8]);
    }
#pragma unroll
    for (int i = 0; i < 3; ++i) {
      int cc = i * 256 + tid;            // this thread's B chunk
      int row = cc >> 3, col = (cc & 7) * 8;
      gload16(Bw + (size_t)(n0 + row) * K + k0 + col, &b_lds[(i * 256 + wave * 64) * 8]);
    }
    __syncthreads();
#pragma unroll
    for (int kk = 0; kk < 2; ++kk) {
      bf16x8 af[MR], bfr[3];
#pragma unroll
      for (int m = 0; m < MR; ++m) {
        int row = wr * (MR * 16) + m * 16 + l15;
        af[m] = ld16(&a_lds[row * BK + kk * 32 + lg * 8]);
      }
#pragma unroll
      for (int n = 0; n < 3; ++n) {
        int row = wc * 48 + n * 16 + l15;
        bfr[n] = ld16(&b_lds[row * BK + kk * 32 + lg * 8]);
      }
#pragma unroll
      for (int m = 0; m < MR; ++m)
#pragma unroll
        for (int n = 0; n < 3; ++n)
          acc[m][n] = __builtin_amdgcn_mfma_f32_16x16x32_bf16(af[m], bfr[n], acc[m][n], 0, 0, 0);
    }
    __syncthreads();
  }

  // epilogue: C row = (lane>>4)*4 + j, col = lane&15 within each 16x16 tile
  if constexpr (MODE == 0) {
    const int base_col = n0 + wc * 48;
    const int s = n0 / Dc;                 // uniform per block (96 | 768)
    if (s == 2) {
      // V -> [bh][d][L]: pack 4 consecutive tokens (j) per store
#pragma unroll
      for (int m = 0; m < 4; ++m) {
        int lq = m0 + wr * 64 + m * 16 + lg * 4;
        int b = lq >> 11, lql = lq & 2047;
#pragma unroll
        for (int n = 0; n < 3; ++n) {
          int cbase = base_col + n * 16;
          int h = (cbase % Dc) >> 6;
          int d = (cbase & 63) + l15;
          float bv = bias[cbase + l15];
          ushort4 o;
#pragma unroll
          for (int j = 0; j < 4; ++j)
            ((unsigned short*)&o)[j] = f2bf(acc[m][n][j] + bv);
          *reinterpret_cast<ushort4*>(
              vtb + ((size_t)(b * Hc + h) * HDc + d) * Lc + lql) = o;
        }
      }
    } else {
      // Q/K -> [bh][L][64]: per-wave LDS patch (16 x 48), then 16B vector stores
      unsigned short* dst = (s == 0) ? qb : kb;
      const float sc = (s == 0) ? (ATT_SCALE * LOG2E) : 1.0f;
#pragma unroll
      for (int m = 0; m < 4; ++m) {
#pragma unroll
        for (int n = 0; n < 3; ++n) {
          float bv = bias[base_col + n * 16 + l15];
#pragma unroll
          for (int j = 0; j < 4; ++j)
            qk_patch[wave][lg * 4 + j][n * 16 + l15] =
                f2bf((acc[m][n][j] + bv) * sc);
        }
        // 16 rows x 6 chunks of 16B = 96 tasks; each chunk lies within one head
#pragma unroll
        for (int i = 0; i < 2; ++i) {
          int task = i * 64 + lane;
          if (task < 96) {
            int r = task / 6, ch = task - r * 6;
            int gcol = base_col + ch * 8;
            int h = (gcol % Dc) >> 6;
            int d0 = gcol & 63;
            int lq = m0 + wr * 64 + m * 16 + r;
            int b = lq >> 11, lql = lq & 2047;
            u32x4 v = *reinterpret_cast<const u32x4*>(&qk_patch[wave][r][ch * 8]);
            *reinterpret_cast<u32x4*>(
                dst + ((size_t)(b * Hc + h) * Lc + lql) * HDc + d0) = v;
          }
        }
      }
    }
  } else {
#pragma unroll
    for (int m = 0; m < MR; ++m) {
      int row_base = m0 + wr * (MR * 16) + m * 16 + lg * 4;
#pragma unroll
      for (int n = 0; n < 3; ++n) {
        int col = n0 + wc * 48 + n * 16 + l15;
        float bv = bias[col];
#pragma unroll
        for (int j = 0; j < 4; ++j)
          Y[(size_t)(row_base + j) * Dc + col] = acc[m][n][j] + bv;
      }
    }
  }
}

// ---------------- flash attention v7: q-doubled waves (half LDS reads per FLOP) --------
// R19: R5 model (validated): wall/iter == SUM of pipes; LDS-read is the largest term
// (12 waves x 8 ds_read_b128/iter ~ 1156cy of 3480). K/V fragment reads are REUSABLE
// across Q-tiles: one wave now serves 64 q (two 32-col Q-tile B-operands), so each
// K-read feeds 2 QK MFMAs and each V-read feeds 2 PV MFMAs -> per-q LDS traffic HALVED,
// per-q MFMA/exp/pack unchanged. Block = 64 q rows, 128 threads (2 waves); wave g takes
// kv sub-half g. Staging: each wave owns 4 chunks (j = wave*4+jj); layout/swizzle/rings
// identical to v5; counted waits scale: steady outstanding {K(t+2):4,V(t+1):4,K(t+3):4}
// -> vmcnt(4) leaves K(t+3) in flight (tail traced, mirrors v5). Grid stays 768
// (24 bh x 32 qblocks), LDS 48KB -> 3 blocks/CU exact; 6 waves/CU.
// __launch_bounds__(128,2) caps VGPR at 256 so 3-block residency is guaranteed.
// Schedule skeleton (T15 cross-iter QK(t+1) overlap, one barrier/iter, V staged after
// barrier, row-sums on MFMA pipe) is UNTOUCHED — R6's lesson.
__global__ __launch_bounds__(128, 2) void attn_kernel(
    const unsigned short* __restrict__ qb,   // [BH][L][64], pre-scaled by SCALE*LOG2E
    const unsigned short* __restrict__ kb,   // [BH][L][64]
    const unsigned short* __restrict__ vtb,  // [BH][64][L] transposed
    const float* __restrict__ mb,            // [B][L]: 0 / -1e30
    const int* __restrict__ mflag,           // [B][L/64] any-masked flag
    unsigned short* __restrict__ aout) {     // [B][L][768]
  __shared__ alignas(16) unsigned short k_lds[4][4096];  // K ring-4, 8KB tiles, swizzled
  __shared__ alignas(16) unsigned short v_lds[2][4096];  // V ring-2
  __shared__ float l_lds[2][32];
  const int tid = threadIdx.x;
  const int lane = tid & 63;
  const int l31 = lane & 31;
  const int hi = lane >> 5;
  const int wave = tid >> 6;                 // 0..1
  const int g = wave;                        // kv sub-half of the 64-kv tile
  // XCD-clustered work assignment (768 = 8 XCD x 3 bh x 32 qblocks)
  const int f = blockIdx.x;
  const int loc = f >> 3;                    // 0..95
  const int bh = (f & 7) * 3 + (loc >> 5);
  const int b = bh / Hc, h = bh % Hc;
  const int q0 = (loc & 31) * 64;            // block's 64 q rows

  const unsigned short* Kbh = kb + (size_t)bh * Lc * HDc;
  const unsigned short* Vbh = vtb + (size_t)bh * HDc * Lc;
  const float* mbb = mb + b * Lc + hi * 4;
  const int* mfp = mflag + b * (Lc / 64);

  // mask-tile flags -> one 32-bit mask (keeps the main loop free of vector loads)
  unsigned long long mbits;
  {
    int mv = (lane < 32) ? mfp[lane] : 0;
    mbits = __ballot(mv != 0);
  }

  // Q as B-operand, TWO 32-q tiles per wave: lane holds Q[q0+qt*32+l31][c*16+hi*8+j]
  bf16x8 qf[2][4];
#pragma unroll
  for (int qt = 0; qt < 2; ++qt) {
    const unsigned short* Qp = qb + ((size_t)bh * Lc + q0 + qt * 32 + l31) * HDc + hi * 8;
#pragma unroll
    for (int c = 0; c < 4; ++c) qf[qt][c] = ld16(Qp + c * 16);
  }

  // all-ones A-frag for MFMA row-sums
  bf16x8 onesf;
  {
    u32x4 ow = {0x3F803F80u, 0x3F803F80u, 0x3F803F80u, 0x3F803F80u};
    onesf = __builtin_bit_cast(bf16x8, ow);
  }

  f32x16 accO[2][2] = {};  // [qt][dt] O^T[d][q]: d = dt*32+crow, q = q0+qt*32+l31
  f32x16 accL[2] = {};     // [qt] all rows = running sum over this wave's kv rows

  // staging: wave owns chunks j = wave*4+jj (8 full rows each), inverse-swizzled cols.
  const unsigned short* kp[4];
  const unsigned short* vp[4];
#pragma unroll
  for (int jj = 0; jj < 4; ++jj) {
    int j = wave * 4 + jj;
    int r8 = j * 8 + (lane >> 3);
    int csw = (((lane & 7) ^ (lane >> 3) ^ (j & 3))) << 3;
    kp[jj] = Kbh + (size_t)r8 * HDc + csw;
    vp[jj] = Vbh + (size_t)r8 * Lc + csw;
  }

#define STAGEK(buf)                                                   \
  {                                                                   \
    _Pragma("unroll")                                                 \
    for (int jj = 0; jj < 4; ++jj) {                                  \
      gload16(kp[jj], &k_lds[buf][(wave * 4 + jj) * 512]);            \
      kp[jj] += 64 * HDc;                                             \
    }                                                                 \
  }
#define STAGEV(buf)                                                   \
  {                                                                   \
    _Pragma("unroll")                                                 \
    for (int jj = 0; jj < 4; ++jj) {                                  \
      gload16(vp[jj], &v_lds[buf][(wave * 4 + jj) * 512]);            \
      vp[jj] += 64;                                                   \
    }                                                                 \
  }

  const int swz = ((l31 & 7) ^ (l31 >> 3)) << 3;   // read-side XOR (row bits 0..4)
  const int krow = (g * 32 + l31) * 64;            // this wave's K row base (shorts)

  // ---- prologue: K0,K1,V0 landed; K2,V1 in flight; s = QK(tile0) for both q-tiles ----
  STAGEK(0) STAGEK(1) STAGEV(0)
  asm volatile("s_waitcnt vmcnt(0)" ::: "memory");
  __builtin_amdgcn_s_barrier();
  f32x16 s[2] = {};
#pragma unroll
  for (int c = 0; c < 4; ++c) {
    int ch = (((c * 2 + hi) << 3) ^ swz);
    bf16x8 kread = ld16(&k_lds[0][0] + krow + ch);
    s[0] = __builtin_amdgcn_mfma_f32_32x32x16_bf16(kread, qf[0][c], s[0], 0, 0, 0);
    s[1] = __builtin_amdgcn_mfma_f32_32x32x16_bf16(kread, qf[1][c], s[1], 0, 0, 0);
  }
  STAGEK(2) STAGEV(1)

  constexpr int NSTEP = Lc / 64;   // 32
  for (int t = 0; t < NSTEP; ++t) {
    if (t + 3 < NSTEP) STAGEK((t + 3) & 3)

    // ---- s2 = QK(t+1) both q-tiles: K-read shared, overlaps softmax(t) below ----
    f32x16 s2[2] = {};
    if (t + 1 < NSTEP) {
      const unsigned short* kl = &k_lds[(t + 1) & 3][0];
      __builtin_amdgcn_s_setprio(1);
#pragma unroll
      for (int c = 0; c < 4; ++c) {
        int ch = (((c * 2 + hi) << 3) ^ swz);
        bf16x8 kread = ld16(kl + krow + ch);
        s2[0] = __builtin_amdgcn_mfma_f32_32x32x16_bf16(kread, qf[0][c], s2[0], 0, 0, 0);
        s2[1] = __builtin_amdgcn_mfma_f32_32x32x16_bf16(kread, qf[1][c], s2[1], 0, 0, 0);
      }
      __builtin_amdgcn_s_setprio(0);
    }

    // ---- softmax(t): mask (loads shared across q-tiles), exp2, pack ----
    if ((mbits >> t) & 1ull) {
      const int kvt = t * 64 + g * 32;
#pragma unroll
      for (int gg = 0; gg < 4; ++gg) {
        float4 m0v = *reinterpret_cast<const float4*>(mbb + kvt + gg * 8);
#pragma unroll
        for (int qt = 0; qt < 2; ++qt) {
          s[qt][gg * 4 + 0] += m0v.x; s[qt][gg * 4 + 1] += m0v.y;
          s[qt][gg * 4 + 2] += m0v.z; s[qt][gg * 4 + 3] += m0v.w;
        }
      }
    }
#pragma unroll
    for (int qt = 0; qt < 2; ++qt)
#pragma unroll
      for (int i = 0; i < 16; ++i) s[qt][i] = __builtin_amdgcn_exp2f(s[qt][i]);
    bf16x8 pf[2][2];
#pragma unroll
    for (int qt = 0; qt < 2; ++qt)
#pragma unroll
      for (int c = 0; c < 2; ++c) {
        const int o = c * 8;
        unsigned pk01 = cvtpk(s[qt][o + 0], s[qt][o + 1]);
        unsigned pk23 = cvtpk(s[qt][o + 2], s[qt][o + 3]);
        unsigned pk45 = cvtpk(s[qt][o + 4], s[qt][o + 5]);
        unsigned pk67 = cvtpk(s[qt][o + 6], s[qt][o + 7]);
        asm("v_permlane32_swap_b32 %0, %1" : "+v"(pk01), "+v"(pk45));
        asm("v_permlane32_swap_b32 %0, %1" : "+v"(pk23), "+v"(pk67));
        u32x4 w = {pk01, pk23, pk45, pk67};
        pf[qt][c] = __builtin_bit_cast(bf16x8, w);
      }
    // ---- row sums on the MFMA pipe ----
#pragma unroll
    for (int qt = 0; qt < 2; ++qt) {
      accL[qt] = __builtin_amdgcn_mfma_f32_32x32x16_bf16(onesf, pf[qt][0], accL[qt], 0, 0, 0);
      accL[qt] = __builtin_amdgcn_mfma_f32_32x32x16_bf16(onesf, pf[qt][1], accL[qt], 0, 0, 0);
    }
    // ---- O^T += V^T P^T: V-read shared across q-tiles ----
    {
      const unsigned short* vl = &v_lds[t & 1][0];
      __builtin_amdgcn_s_setprio(1);
#pragma unroll
      for (int dt = 0; dt < 2; ++dt) {
#pragma unroll
        for (int c = 0; c < 2; ++c) {
          int chv = (((g * 4 + c * 2 + hi) << 3) ^ swz);
          bf16x8 vread = ld16(vl + (dt * 32 + l31) * 64 + chv);
          accO[0][dt] = __builtin_amdgcn_mfma_f32_32x32x16_bf16(vread, pf[0][c], accO[0][dt], 0, 0, 0);
          accO[1][dt] = __builtin_amdgcn_mfma_f32_32x32x16_bf16(vread, pf[1][c], accO[1][dt], 0, 0, 0);
        }
      }
      __builtin_amdgcn_s_setprio(0);
    }
    // ---- end of iter: counted drain of {K(t+2):4, V(t+1):4}; K(t+3) stays in flight ----
    if (t < NSTEP - 3) {
      asm volatile("s_waitcnt vmcnt(4)" ::: "memory");
    } else {
      asm volatile("s_waitcnt vmcnt(0)" ::: "memory");
    }
    __builtin_amdgcn_s_barrier();
    __builtin_amdgcn_sched_barrier(0);
    if (t + 2 < NSTEP) STAGEV((t) & 1)   // V(t+2) -> vbuf[t&1], just freed by PV(t)
#pragma unroll
    for (int qt = 0; qt < 2; ++qt) s[qt] = s2[qt];
  }

  // ---- merge kv sub-halves: g=1 publishes into dead k_lds, g=0 combines & writes ----
  __syncthreads();
  float* mO = (float*)&k_lds[0][0];   // [qt*32+dt*16+i][lane] floats = 16KB, lane-major
  if (g == 1) {
#pragma unroll
    for (int qt = 0; qt < 2; ++qt) {
#pragma unroll
      for (int dt = 0; dt < 2; ++dt)
#pragma unroll
        for (int i = 0; i < 16; ++i)
          mO[(qt * 32 + dt * 16 + i) * 64 + lane] = accO[qt][dt][i];
      if (hi == 0) l_lds[qt][l31] = accL[qt][0];
    }
  }
  __syncthreads();
  if (g == 0) {
#pragma unroll
    for (int qt = 0; qt < 2; ++qt) {
      float rl = 1.0f / (accL[qt][0] + l_lds[qt][l31]);
      const int q = q0 + qt * 32 + l31;
      unsigned short* op = aout + ((size_t)(b * Lc + q)) * Dc + h * HDc;
#pragma unroll
      for (int dt = 0; dt < 2; ++dt)
#pragma unroll
        for (int gg = 0; gg < 4; ++gg) {
          ushort4 o;
#pragma unroll
          for (int j = 0; j < 4; ++j) {
            int i = gg * 4 + j;
            float v = (accO[qt][dt][i] + mO[(qt * 32 + dt * 16 + i) * 64 + lane]) * rl;
            ((unsigned short*)&o)[j] = f2bf(v);
          }
          *reinterpret_cast<ushort4*>(op + dt * 32 + gg * 8 + hi * 4) = o;
        }
    }
  }
}

// ---------------- launch ----------------
extern "C" void kernel_launch(void* const* d_in, const int* in_sizes, int n_in,
                              void* d_out, int out_size, void* d_ws, size_t ws_size,
                              hipStream_t stream) {
  const float* x    = (const float*)d_in[0];
  const int*   mask = (const int*)d_in[1];
  const float* Wqkv = (const float*)d_in[2];
  const float* bqkv = (const float*)d_in[3];
  const float* Wout = (const float*)d_in[4];
  const float* bout = (const float*)d_in[5];
  float* out = (float*)d_out;

  constexpr size_t NX   = (size_t)NTOK * Dc;      // 3145728
  constexpr size_t NWQ  = (size_t)QKVN * Dc;      // 1769472
  constexpr size_t NWO  = (size_t)Dc * Dc;        // 589824
  unsigned short* w = (unsigned short*)d_ws;
  unsigned short* xb    = w;            w += NX;
  unsigned short* wqkvb = w;            w += NWQ;
  unsigned short* woutb = w;            w += NWO;
  unsigned short* qbuf  = w;            w += NX;
  unsigned short* kbuf  = w;            w += NX;
  unsigned short* vtb   = w;            w += NX;
  unsigned short* aoutb = w;            w += NX;
  float* mbf = (float*)w;               w += 2 * NTOK;
  int* mflag = (int*)w;

  // fused converts + mask aux (one launch instead of four)
  prep_kernel<<<5392, 256, 0, stream>>>(x, Wqkv, Wout, mask, xb, wqkvb, woutb, mbf, mflag);

  // QKV projection: M=4096, N=2304, K=768 — grid 32x24 = 768 = 3 blocks/CU exact
  gemm_bt<0><<<(NTOK / 128) * (QKVN / 96), 256, 0, stream>>>(
      xb, wqkvb, bqkv, qbuf, kbuf, vtb, nullptr, NTOK, QKVN, Dc);

  // attention: 768 blocks x 128 threads (8 XCD x 3 bh x 32 qblocks; 2 waves = 2 kv-subhalves,
  // each wave serves all 64 q via two 32-col Q-tiles)
  attn_kernel<<<dim3(768), 128, 0, stream>>>(qbuf, kbuf, vtb, mbf, mflag, aoutb);

  // output projection: M=4096, N=768, K=768 — grid 64x8 = 512 = 2 blocks/CU exact
  gemm_bt<1><<<(NTOK / 64) * (Dc / 96), 256, 0, stream>>>(
      aoutb, woutb, bout, nullptr, nullptr, nullptr, out, NTOK, Dc, Dc);
}

// Round 9
// 92.897 us; speedup vs baseline: 1.0417x; 1.0417x over previous
//
#include <hip/hip_runtime.h>
#include <hip/hip_bf16.h>

#define DEV __device__ __forceinline__

typedef __bf16 bf16_t;
typedef bf16_t bf16x8 __attribute__((ext_vector_type(8)));
typedef float f32x4 __attribute__((ext_vector_type(4)));
typedef float f32x16 __attribute__((ext_vector_type(16)));
typedef unsigned int u32x4 __attribute__((ext_vector_type(4)));

constexpr int Bc = 2, Lc = 2048, Dc = 768, Hc = 12, HDc = 64;
constexpr int NTOK = Bc * Lc;     // 4096
constexpr int QKVN = 3 * Dc;      // 2304
constexpr float ATT_SCALE = 0.125f;          // 64^-0.5
constexpr float LOG2E = 1.44269504088896f;

DEV unsigned short f2bf(float f) {
  unsigned int u = __builtin_bit_cast(unsigned int, f);
  u += 0x7FFFu + ((u >> 16) & 1u);   // round-to-nearest-even
  return (unsigned short)(u >> 16);
}

DEV bf16x8 ld16(const unsigned short* p) {
  return __builtin_bit_cast(bf16x8, *reinterpret_cast<const u32x4*>(p));
}

DEV unsigned cvtpk(float lo, float hi) {
  unsigned r;
  asm("v_cvt_pk_bf16_f32 %0, %1, %2" : "=v"(r) : "v"(lo), "v"(hi));
  return r;
}

// async global->LDS, 16B per lane; lds dest = wave-uniform base + lane*16 (HW);
// global src address is PER-LANE (m173).
DEV void gload16(const unsigned short* g, unsigned short* l) {
  __builtin_amdgcn_global_load_lds(
      (const __attribute__((address_space(1))) unsigned int*)g,
      (__attribute__((address_space(3))) unsigned int*)l, 16, 0, 0);
}

// ---------------- fused prep: 3 bf16 converts + mask aux in ONE launch ----------------
// blocks [0,3072): x  [3072,4800): Wqkv  [4800,5376): Wout  [5376,5392): mask
__global__ __launch_bounds__(256) void prep_kernel(
    const float* __restrict__ x, const float* __restrict__ Wqkv,
    const float* __restrict__ Wout, const int* __restrict__ mask,
    unsigned short* __restrict__ xb, unsigned short* __restrict__ wqkvb,
    unsigned short* __restrict__ woutb, float* __restrict__ mb,
    int* __restrict__ mflag) {
  const int bid = blockIdx.x, tid = threadIdx.x;
  const float* src; unsigned short* dst; int base;
  if (bid < 3072)      { src = x;    dst = xb;    base = bid; }
  else if (bid < 4800) { src = Wqkv; dst = wqkvb; base = bid - 3072; }
  else if (bid < 5376) { src = Wout; dst = woutb; base = bid - 4800; }
  else {
    int i = (bid - 5376) * 256 + tid;
    int mv = mask[i];
    mb[i] = mv ? 0.f : -1e30f;
    unsigned long long anyz = __ballot(mv == 0);
    if ((tid & 63) == 0) mflag[i >> 6] = (anyz != 0ull) ? 1 : 0;
    return;
  }
  int i = (base * 256 + tid) * 4;
  float4 v = *reinterpret_cast<const float4*>(src + i);
  ushort4 o;
  o.x = f2bf(v.x); o.y = f2bf(v.y); o.z = f2bf(v.z); o.w = f2bf(v.w);
  *reinterpret_cast<ushort4*>(dst + i) = o;
}

// ---------------- bf16 GEMM, C[m,n] = sum_k A[m,k]*B[n,k] + bias[n] --------
// R16 (grid balance): MODE 0: BM=128,BN=96 -> grid 32x24=768 = exactly 3 blocks/CU
// (old 576 @ residency 3 -> CUs carried 2 or 3 -> 75% util). MODE 1: BM=64,BN=96 ->
// grid 64x8=512 = exactly 2/CU, 8 waves/CU (old 192 blocks left 64 CUs idle).
// BN=96: 96|768 so no tile crosses a q/k/v third; 16-col frags never cross a 64-col
// head boundary (frag col starts are multiples of 16 and 16|64).
// XCD swizzle (bijective, nwg%8==0) with col-major tile order: each XCD's 96 (resp 64)
// blocks share 3 (resp 1) B-column-tiles -> B slice resident in that XCD's L2.
// MODE 0 epilogue: scatter to q/k/vT bf16 buffers (Q pre-scaled); Q/K via per-wave LDS
// patch -> 16B vector stores.  MODE 1: write f32 Y.
template <int MODE>
__global__ __launch_bounds__(256) void gemm_bt(
    const unsigned short* __restrict__ A,   // [M][K] bf16
    const unsigned short* __restrict__ Bw,  // [N][K] bf16
    const float* __restrict__ bias,         // [N]
    unsigned short* __restrict__ qb, unsigned short* __restrict__ kb,
    unsigned short* __restrict__ vtb,
    float* __restrict__ Y,
    int M, int N, int K) {
  constexpr int BM = (MODE == 0) ? 128 : 64;
  constexpr int BN = 96, BK = 64;
  constexpr int AI = BM * BK / 2048;        // A gload iters: 4 / 2
  constexpr int MR = BM / 32;               // m frags per wave: 4 / 2
  __shared__ alignas(16) unsigned short a_lds[BM * BK];  // linear [row][64]
  __shared__ alignas(16) unsigned short b_lds[BN * BK];
  __shared__ alignas(16) unsigned short qk_patch[(MODE == 0) ? 4 : 1][16][56];

  const int tid = threadIdx.x;
  const int lane = tid & 63;
  const int l15 = lane & 15, lg = lane >> 4;
  const int wave = tid >> 6;
  const int wr = wave >> 1, wc = wave & 1;

  const int nm = M / BM;
  const int nwg = nm * (N / BN);
  // bijective XCD swizzle (nwg % 8 == 0), then col-major tile order
  const int t = (blockIdx.x & 7) * (nwg >> 3) + (blockIdx.x >> 3);
  const int m0 = (t % nm) * BM;
  const int n0 = (t / nm) * BN;

  f32x4 acc[MR][3] = {};

  for (int k0 = 0; k0 < K; k0 += BK) {
#pragma unroll
    for (int i = 0; i < AI; ++i) {
      int cc = i * 256 + tid;            // this thread's A chunk
      int row = cc >> 3, col = (cc & 7) * 8;
      gload16(A + (size_t)(m0 + row) * K + k0 + col, &a_lds[(i * 256 + wave * 64) * 8]);
    }
#pragma unroll
    for (int i = 0; i < 3; ++i) {
      int cc = i * 256 + tid;            // this thread's B chunk
      int row = cc >> 3, col = (cc & 7) * 8;
      gload16(Bw + (size_t)(n0 + row) * K + k0 + col, &b_lds[(i * 256 + wave * 64) * 8]);
    }
    __syncthreads();
#pragma unroll
    for (int kk = 0; kk < 2; ++kk) {
      bf16x8 af[MR], bfr[3];
#pragma unroll
      for (int m = 0; m < MR; ++m) {
        int row = wr * (MR * 16) + m * 16 + l15;
        af[m] = ld16(&a_lds[row * BK + kk * 32 + lg * 8]);
      }
#pragma unroll
      for (int n = 0; n < 3; ++n) {
        int row = wc * 48 + n * 16 + l15;
        bfr[n] = ld16(&b_lds[row * BK + kk * 32 + lg * 8]);
      }
#pragma unroll
      for (int m = 0; m < MR; ++m)
#pragma unroll
        for (int n = 0; n < 3; ++n)
          acc[m][n] = __builtin_amdgcn_mfma_f32_16x16x32_bf16(af[m], bfr[n], acc[m][n], 0, 0, 0);
    }
    __syncthreads();
  }

  // epilogue: C row = (lane>>4)*4 + j, col = lane&15 within each 16x16 tile
  if constexpr (MODE == 0) {
    const int base_col = n0 + wc * 48;
    const int s = n0 / Dc;                 // uniform per block (96 | 768)
    if (s == 2) {
      // V -> [bh][d][L]: pack 4 consecutive tokens (j) per store
#pragma unroll
      for (int m = 0; m < 4; ++m) {
        int lq = m0 + wr * 64 + m * 16 + lg * 4;
        int b = lq >> 11, lql = lq & 2047;
#pragma unroll
        for (int n = 0; n < 3; ++n) {
          int cbase = base_col + n * 16;
          int h = (cbase % Dc) >> 6;
          int d = (cbase & 63) + l15;
          float bv = bias[cbase + l15];
          ushort4 o;
#pragma unroll
          for (int j = 0; j < 4; ++j)
            ((unsigned short*)&o)[j] = f2bf(acc[m][n][j] + bv);
          *reinterpret_cast<ushort4*>(
              vtb + ((size_t)(b * Hc + h) * HDc + d) * Lc + lql) = o;
        }
      }
    } else {
      // Q/K -> [bh][L][64]: per-wave LDS patch (16 x 48), then 16B vector stores
      unsigned short* dst = (s == 0) ? qb : kb;
      const float sc = (s == 0) ? (ATT_SCALE * LOG2E) : 1.0f;
#pragma unroll
      for (int m = 0; m < 4; ++m) {
#pragma unroll
        for (int n = 0; n < 3; ++n) {
          float bv = bias[base_col + n * 16 + l15];
#pragma unroll
          for (int j = 0; j < 4; ++j)
            qk_patch[wave][lg * 4 + j][n * 16 + l15] =
                f2bf((acc[m][n][j] + bv) * sc);
        }
        // 16 rows x 6 chunks of 16B = 96 tasks; each chunk lies within one head
#pragma unroll
        for (int i = 0; i < 2; ++i) {
          int task = i * 64 + lane;
          if (task < 96) {
            int r = task / 6, ch = task - r * 6;
            int gcol = base_col + ch * 8;
            int h = (gcol % Dc) >> 6;
            int d0 = gcol & 63;
            int lq = m0 + wr * 64 + m * 16 + r;
            int b = lq >> 11, lql = lq & 2047;
            u32x4 v = *reinterpret_cast<const u32x4*>(&qk_patch[wave][r][ch * 8]);
            *reinterpret_cast<u32x4*>(
                dst + ((size_t)(b * Hc + h) * Lc + lql) * HDc + d0) = v;
          }
        }
      }
    }
  } else {
#pragma unroll
    for (int m = 0; m < MR; ++m) {
      int row_base = m0 + wr * (MR * 16) + m * 16 + lg * 4;
#pragma unroll
      for (int n = 0; n < 3; ++n) {
        int col = n0 + wc * 48 + n * 16 + l15;
        float bv = bias[col];
#pragma unroll
        for (int j = 0; j < 4; ++j)
          Y[(size_t)(row_base + j) * Dc + col] = acc[m][n][j] + bv;
      }
    }
  }
}

// ---------------- flash attention v5s: R5 kernel + entry stagger ONLY ----------------
// R20: R8 (q-doubling) hit the pre-commit tripwire (50.8us, occupancy 13%): at 1.5
// waves/SIMD no TLP covers the chain latency. Reverted to the exact R5 form (46.6us,
// VGPR 84, 12 waves/CU). ONE new lever, in isolation this time (R6 bundled it with
// unroll/VGPR changes that regressed): s_sleep entry skew by blockIdx%3 (~0/1k/2k cyc).
// Tests the phase-lock theory cleanly: R5 model says wall/iter == SUM of pipe terms
// (zero cross-pipe overlap among the 3 co-resident blocks). Stagger costs <=2k cyc
// one-time (~0.3us) if the theory is wrong; ~25% if right.
__global__ __launch_bounds__(256) void attn_kernel(
    const unsigned short* __restrict__ qb,   // [BH][L][64], pre-scaled by SCALE*LOG2E
    const unsigned short* __restrict__ kb,   // [BH][L][64]
    const unsigned short* __restrict__ vtb,  // [BH][64][L] transposed
    const float* __restrict__ mb,            // [B][L]: 0 / -1e30
    const int* __restrict__ mflag,           // [B][L/64] any-masked flag
    unsigned short* __restrict__ aout) {     // [B][L][768]
  __shared__ alignas(16) unsigned short k_lds[4][4096];  // K ring-4, 8KB tiles, swizzled
  __shared__ alignas(16) unsigned short v_lds[2][4096];  // V ring-2
  __shared__ float l_lds[2][32];
  const int tid = threadIdx.x;
  const int lane = tid & 63;
  const int l31 = lane & 31;
  const int hi = lane >> 5;
  const int wave = tid >> 6;                 // 0..3
  const int ws = wave & 1;                   // q sub-tile (32 rows)
  const int g = wave >> 1;                   // kv sub-half of the 64-kv tile
  // XCD-clustered work assignment (768 = 8 XCD x 3 bh x 32 qblocks)
  const int f = blockIdx.x;
  const int loc = f >> 3;                    // 0..95
  const int bh = (f & 7) * 3 + (loc >> 5);
  const int b = bh / Hc, h = bh % Hc;
  const int q0 = (loc & 31) * 64 + ws * 32;

  // ---- R20: entry phase-stagger (the ONLY change vs R5) ----
  {
    const int ph = f % 3;
    if (ph == 1) { asm volatile("s_sleep 8\n\ts_sleep 8" ::: "memory"); }
    else if (ph == 2) { asm volatile("s_sleep 8\n\ts_sleep 8\n\ts_sleep 8\n\ts_sleep 8" ::: "memory"); }
  }

  const unsigned short* Kbh = kb + (size_t)bh * Lc * HDc;
  const unsigned short* Vbh = vtb + (size_t)bh * HDc * Lc;
  const float* mbb = mb + b * Lc + hi * 4;
  const int* mfp = mflag + b * (Lc / 64);

  // mask-tile flags -> one 32-bit mask (keeps the main loop free of vector loads)
  unsigned long long mbits;
  {
    int mv = (lane < 32) ? mfp[lane] : 0;
    mbits = __ballot(mv != 0);
  }

  // Q as B-operand: lane holds Q[q0+l31][c*16 + hi*8 + j]
  bf16x8 qf[4];
  {
    const unsigned short* Qp = qb + ((size_t)bh * Lc + q0 + l31) * HDc + hi * 8;
#pragma unroll
    for (int c = 0; c < 4; ++c) qf[c] = ld16(Qp + c * 16);
  }

  // all-ones A-frag for MFMA row-sums
  bf16x8 onesf;
  {
    u32x4 ow = {0x3F803F80u, 0x3F803F80u, 0x3F803F80u, 0x3F803F80u};
    onesf = __builtin_bit_cast(bf16x8, ow);
  }

  f32x16 accO[2] = {};   // O^T[d][q]: d = dt*32 + (reg&3)+8*(reg>>2)+4*hi, q = q0+l31
  f32x16 accL = {};      // all rows = running sum over this wave's kv rows, col = q

  // staging: wave w owns chunks j={2w,2w+1} = 8 full rows each, inverse-swizzled cols.
  const int j0 = wave * 2, j1 = j0 + 1;
  const int r80 = j0 * 8 + (lane >> 3), r81 = r80 + 8;
  const int csw0 = (((lane & 7) ^ (lane >> 3) ^ (j0 & 3))) << 3;
  const int csw1 = (((lane & 7) ^ (lane >> 3) ^ (j1 & 3))) << 3;
  const unsigned short* kp0 = Kbh + (size_t)r80 * HDc + csw0;
  const unsigned short* kp1 = Kbh + (size_t)r81 * HDc + csw1;
  const unsigned short* vp0 = Vbh + (size_t)r80 * Lc + csw0;
  const unsigned short* vp1 = Vbh + (size_t)r81 * Lc + csw1;

#define STAGEK(buf)                               \
  {                                               \
    gload16(kp0, &k_lds[buf][j0 * 512]);          \
    gload16(kp1, &k_lds[buf][j1 * 512]);          \
    kp0 += 64 * HDc; kp1 += 64 * HDc;             \
  }
#define STAGEV(buf)                               \
  {                                               \
    gload16(vp0, &v_lds[buf][j0 * 512]);          \
    gload16(vp1, &v_lds[buf][j1 * 512]);          \
    vp0 += 64; vp1 += 64;                         \
  }

  const int swz = ((l31 & 7) ^ (l31 >> 3)) << 3;   // read-side XOR (row bits 0..4)
  const int krow = (g * 32 + l31) * 64;            // this wave's K row base (shorts)

  // ---- prologue: K0,K1,V0 landed; K2,V1 in flight; S = QK(tile0) ----
  STAGEK(0) STAGEK(1) STAGEV(0)
  asm volatile("s_waitcnt vmcnt(0)" ::: "memory");
  __builtin_amdgcn_s_barrier();
  f32x16 s = {};
#pragma unroll
  for (int c = 0; c < 4; ++c) {
    int ch = (((c * 2 + hi) << 3) ^ swz);
    s = __builtin_amdgcn_mfma_f32_32x32x16_bf16(
        ld16(&k_lds[0][0] + krow + ch), qf[c], s, 0, 0, 0);
  }
  STAGEK(2) STAGEV(1)

  constexpr int NSTEP = Lc / 64;   // 32
  for (int t = 0; t < NSTEP; ++t) {
    if (t + 3 < NSTEP) STAGEK((t + 3) & 3)

    // ---- S' = QK(t+1): independent MFMA chain, overlaps softmax(t) below ----
    f32x16 s2 = {};
    if (t + 1 < NSTEP) {
      const unsigned short* kl = &k_lds[(t + 1) & 3][0];
      __builtin_amdgcn_s_setprio(1);
#pragma unroll
      for (int c = 0; c < 4; ++c) {
        int ch = (((c * 2 + hi) << 3) ^ swz);
        s2 = __builtin_amdgcn_mfma_f32_32x32x16_bf16(
            ld16(kl + krow + ch), qf[c], s2, 0, 0, 0);
      }
      __builtin_amdgcn_s_setprio(0);
    }

    // ---- softmax(t) on s: mask, exp2, pack (no sum chain — sums via MFMA) ----
    if ((mbits >> t) & 1ull) {
      const int kvt = t * 64 + g * 32;
#pragma unroll
      for (int gg = 0; gg < 4; ++gg) {
        float4 m0v = *reinterpret_cast<const float4*>(mbb + kvt + gg * 8);
        s[gg * 4 + 0] += m0v.x; s[gg * 4 + 1] += m0v.y;
        s[gg * 4 + 2] += m0v.z; s[gg * 4 + 3] += m0v.w;
      }
    }
#pragma unroll
    for (int i = 0; i < 16; ++i) s[i] = __builtin_amdgcn_exp2f(s[i]);
    bf16x8 pf[2];
#pragma unroll
    for (int c = 0; c < 2; ++c) {
      const int o = c * 8;
      unsigned pk01 = cvtpk(s[o + 0], s[o + 1]);
      unsigned pk23 = cvtpk(s[o + 2], s[o + 3]);
      unsigned pk45 = cvtpk(s[o + 4], s[o + 5]);
      unsigned pk67 = cvtpk(s[o + 6], s[o + 7]);
      asm("v_permlane32_swap_b32 %0, %1" : "+v"(pk01), "+v"(pk45));
      asm("v_permlane32_swap_b32 %0, %1" : "+v"(pk23), "+v"(pk67));
      u32x4 w = {pk01, pk23, pk45, pk67};
      pf[c] = __builtin_bit_cast(bf16x8, w);
    }
    // ---- row sums on the MFMA pipe ----
    accL = __builtin_amdgcn_mfma_f32_32x32x16_bf16(onesf, pf[0], accL, 0, 0, 0);
    accL = __builtin_amdgcn_mfma_f32_32x32x16_bf16(onesf, pf[1], accL, 0, 0, 0);
    // ---- O^T += V^T P^T over this wave's 32 kv rows ----
    {
      const unsigned short* vl = &v_lds[t & 1][0];
      __builtin_amdgcn_s_setprio(1);
#pragma unroll
      for (int dt = 0; dt < 2; ++dt) {
#pragma unroll
        for (int c = 0; c < 2; ++c) {
          int ch = (((g * 4 + c * 2 + hi) << 3) ^ swz);
          accO[dt] = __builtin_amdgcn_mfma_f32_32x32x16_bf16(
              ld16(vl + (dt * 32 + l31) * 64 + ch), pf[c], accO[dt], 0, 0, 0);
        }
      }
      __builtin_amdgcn_s_setprio(0);
    }
    // ---- end of iter: counted drain of {K(t+2), V(t+1)}; K(t+3) stays in flight ----
    if (t < NSTEP - 3) {
      asm volatile("s_waitcnt vmcnt(2)" ::: "memory");
    } else {
      asm volatile("s_waitcnt vmcnt(0)" ::: "memory");
    }
    __builtin_amdgcn_s_barrier();
    __builtin_amdgcn_sched_barrier(0);
    if (t + 2 < NSTEP) STAGEV((t) & 1)   // V(t+2) -> vbuf[t&1], just freed by PV(t)
    s = s2;
  }

  // ---- merge kv sub-halves: g=1 publishes into dead k_lds, g=0 combines & writes ----
  __syncthreads();
  const float l_run = accL[0];
  float* mO = (float*)&k_lds[0][0];   // [ws][32][64] floats = 16KB, lane-major
  if (g == 1) {
#pragma unroll
    for (int dt = 0; dt < 2; ++dt)
#pragma unroll
      for (int i = 0; i < 16; ++i)
        mO[(ws * 32 + dt * 16 + i) * 64 + lane] = accO[dt][i];
    if (hi == 0) l_lds[ws][l31] = l_run;
  }
  __syncthreads();
  if (g == 0) {
    float rl = 1.0f / (l_run + l_lds[ws][l31]);
    const int q = q0 + l31;
    unsigned short* op = aout + ((size_t)(b * Lc + q)) * Dc + h * HDc;
#pragma unroll
    for (int dt = 0; dt < 2; ++dt)
#pragma unroll
      for (int gg = 0; gg < 4; ++gg) {
        ushort4 o;
#pragma unroll
        for (int j = 0; j < 4; ++j) {
          int i = gg * 4 + j;
          float v = (accO[dt][i] + mO[(ws * 32 + dt * 16 + i) * 64 + lane]) * rl;
          ((unsigned short*)&o)[j] = f2bf(v);
        }
        *reinterpret_cast<ushort4*>(op + dt * 32 + gg * 8 + hi * 4) = o;
      }
  }
}

// ---------------- launch ----------------
extern "C" void kernel_launch(void* const* d_in, const int* in_sizes, int n_in,
                              void* d_out, int out_size, void* d_ws, size_t ws_size,
                              hipStream_t stream) {
  const float* x    = (const float*)d_in[0];
  const int*   mask = (const int*)d_in[1];
  const float* Wqkv = (const float*)d_in[2];
  const float* bqkv = (const float*)d_in[3];
  const float* Wout = (const float*)d_in[4];
  const float* bout = (const float*)d_in[5];
  float* out = (float*)d_out;

  constexpr size_t NX   = (size_t)NTOK * Dc;      // 3145728
  constexpr size_t NWQ  = (size_t)QKVN * Dc;      // 1769472
  constexpr size_t NWO  = (size_t)Dc * Dc;        // 589824
  unsigned short* w = (unsigned short*)d_ws;
  unsigned short* xb    = w;            w += NX;
  unsigned short* wqkvb = w;            w += NWQ;
  unsigned short* woutb = w;            w += NWO;
  unsigned short* qbuf  = w;            w += NX;
  unsigned short* kbuf  = w;            w += NX;
  unsigned short* vtb   = w;            w += NX;
  unsigned short* aoutb = w;            w += NX;
  float* mbf = (float*)w;               w += 2 * NTOK;
  int* mflag = (int*)w;

  // fused converts + mask aux (one launch instead of four)
  prep_kernel<<<5392, 256, 0, stream>>>(x, Wqkv, Wout, mask, xb, wqkvb, woutb, mbf, mflag);

  // QKV projection: M=4096, N=2304, K=768 — grid 32x24 = 768 = 3 blocks/CU exact
  gemm_bt<0><<<(NTOK / 128) * (QKVN / 96), 256, 0, stream>>>(
      xb, wqkvb, bqkv, qbuf, kbuf, vtb, nullptr, NTOK, QKVN, Dc);

  // attention: 768 blocks x 256 threads (8 XCD x 3 bh x 32 qblocks; 2 q-subtiles x 2 kv-subhalves)
  attn_kernel<<<dim3(768), 256, 0, stream>>>(qbuf, kbuf, vtb, mbf, mflag, aoutb);

  // output projection: M=4096, N=768, K=768 — grid 64x8 = 512 = 2 blocks/CU exact
  gemm_bt<1><<<(NTOK / 64) * (Dc / 96), 256, 0, stream>>>(
      aoutb, woutb, bout, nullptr, nullptr, nullptr, out, NTOK, Dc, Dc);
}

// Round 10
// 92.252 us; speedup vs baseline: 1.0490x; 1.0070x over previous
//
#include <hip/hip_runtime.h>
#include <hip/hip_bf16.h>

#define DEV __device__ __forceinline__

typedef __bf16 bf16_t;
typedef bf16_t bf16x8 __attribute__((ext_vector_type(8)));
typedef float f32x4 __attribute__((ext_vector_type(4)));
typedef float f32x16 __attribute__((ext_vector_type(16)));
typedef unsigned int u32x4 __attribute__((ext_vector_type(4)));

constexpr int Bc = 2, Lc = 2048, Dc = 768, Hc = 12, HDc = 64;
constexpr int NTOK = Bc * Lc;     // 4096
constexpr int QKVN = 3 * Dc;      // 2304
constexpr float ATT_SCALE = 0.125f;          // 64^-0.5
constexpr float LOG2E = 1.44269504088896f;

DEV unsigned short f2bf(float f) {
  unsigned int u = __builtin_bit_cast(unsigned int, f);
  u += 0x7FFFu + ((u >> 16) & 1u);   // round-to-nearest-even
  return (unsigned short)(u >> 16);
}

DEV bf16x8 ld16(const unsigned short* p) {
  return __builtin_bit_cast(bf16x8, *reinterpret_cast<const u32x4*>(p));
}

DEV unsigned cvtpk(float lo, float hi) {
  unsigned r;
  asm("v_cvt_pk_bf16_f32 %0, %1, %2" : "=v"(r) : "v"(lo), "v"(hi));
  return r;
}

// async global->LDS, 16B per lane; lds dest = wave-uniform base + lane*16 (HW);
// global src address is PER-LANE (m173).
DEV void gload16(const unsigned short* g, unsigned short* l) {
  __builtin_amdgcn_global_load_lds(
      (const __attribute__((address_space(1))) unsigned int*)g,
      (__attribute__((address_space(3))) unsigned int*)l, 16, 0, 0);
}

// ---------------- fused prep: 3 bf16 converts + mask aux in ONE launch ----------------
// blocks [0,3072): x  [3072,4800): Wqkv  [4800,5376): Wout  [5376,5392): mask
__global__ __launch_bounds__(256) void prep_kernel(
    const float* __restrict__ x, const float* __restrict__ Wqkv,
    const float* __restrict__ Wout, const int* __restrict__ mask,
    unsigned short* __restrict__ xb, unsigned short* __restrict__ wqkvb,
    unsigned short* __restrict__ woutb, float* __restrict__ mb,
    int* __restrict__ mflag) {
  const int bid = blockIdx.x, tid = threadIdx.x;
  const float* src; unsigned short* dst; int base;
  if (bid < 3072)      { src = x;    dst = xb;    base = bid; }
  else if (bid < 4800) { src = Wqkv; dst = wqkvb; base = bid - 3072; }
  else if (bid < 5376) { src = Wout; dst = woutb; base = bid - 4800; }
  else {
    int i = (bid - 5376) * 256 + tid;
    int mv = mask[i];
    mb[i] = mv ? 0.f : -1e30f;
    unsigned long long anyz = __ballot(mv == 0);
    if ((tid & 63) == 0) mflag[i >> 6] = (anyz != 0ull) ? 1 : 0;
    return;
  }
  int i = (base * 256 + tid) * 4;
  float4 v = *reinterpret_cast<const float4*>(src + i);
  ushort4 o;
  o.x = f2bf(v.x); o.y = f2bf(v.y); o.z = f2bf(v.z); o.w = f2bf(v.w);
  *reinterpret_cast<ushort4*>(dst + i) = o;
}

// ---------------- bf16 GEMM, C[m,n] = sum_k A[m,k]*B[n,k] + bias[n] --------
// R16 (grid balance): MODE 0: BM=128,BN=96 -> grid 32x24=768 = exactly 3 blocks/CU.
// R21 (gemm1 retile): MODE 1: BM=64,BN=64 -> grid 64x12=768 = exactly 3 blocks/CU,
// 12 waves/CU (was 512=2/CU, 8 waves/CU), and per wave-K-tile 16 MFMA : 8 ds_read_b128
// (ratio 2.0; the old BM=64/BN=96 was 12:10 = 1.2). LDS 16KB.
// BN=96 (MODE 0): 96|768 so no tile crosses a q/k/v third; 16-col frags never cross a
// 64-col head boundary. XCD swizzle (bijective, nwg%8==0) with col-major tile order.
// MODE 0 epilogue: scatter to q/k/vT bf16 buffers (Q pre-scaled); Q/K via per-wave LDS
// patch -> 16B vector stores.  MODE 1: write f32 Y.
template <int MODE>
__global__ __launch_bounds__(256) void gemm_bt(
    const unsigned short* __restrict__ A,   // [M][K] bf16
    const unsigned short* __restrict__ Bw,  // [N][K] bf16
    const float* __restrict__ bias,         // [N]
    unsigned short* __restrict__ qb, unsigned short* __restrict__ kb,
    unsigned short* __restrict__ vtb,
    float* __restrict__ Y,
    int M, int N, int K) {
  constexpr int BM = (MODE == 0) ? 128 : 64;
  constexpr int BN = (MODE == 0) ? 96 : 64;
  constexpr int BK = 64;
  constexpr int HBN = BN / 2;               // per-wave n span: 48 / 32
  constexpr int AI = BM * BK / 2048;        // A gload iters: 4 / 2
  constexpr int BI = BN * BK / 2048;        // B gload iters: 3 / 2
  constexpr int MR = BM / 32;               // m frags per wave: 4 / 2
  constexpr int NR = HBN / 16;              // n frags per wave: 3 / 2
  __shared__ alignas(16) unsigned short a_lds[BM * BK];  // linear [row][64]
  __shared__ alignas(16) unsigned short b_lds[BN * BK];
  __shared__ alignas(16) unsigned short qk_patch[(MODE == 0) ? 4 : 1][16][56];

  const int tid = threadIdx.x;
  const int lane = tid & 63;
  const int l15 = lane & 15, lg = lane >> 4;
  const int wave = tid >> 6;
  const int wr = wave >> 1, wc = wave & 1;

  const int nm = M / BM;
  const int nwg = nm * (N / BN);
  // bijective XCD swizzle (nwg % 8 == 0), then col-major tile order
  const int t = (blockIdx.x & 7) * (nwg >> 3) + (blockIdx.x >> 3);
  const int m0 = (t % nm) * BM;
  const int n0 = (t / nm) * BN;

  f32x4 acc[MR][NR] = {};

  for (int k0 = 0; k0 < K; k0 += BK) {
#pragma unroll
    for (int i = 0; i < AI; ++i) {
      int cc = i * 256 + tid;            // this thread's A chunk
      int row = cc >> 3, col = (cc & 7) * 8;
      gload16(A + (size_t)(m0 + row) * K + k0 + col, &a_lds[(i * 256 + wave * 64) * 8]);
    }
#pragma unroll
    for (int i = 0; i < BI; ++i) {
      int cc = i * 256 + tid;            // this thread's B chunk
      int row = cc >> 3, col = (cc & 7) * 8;
      gload16(Bw + (size_t)(n0 + row) * K + k0 + col, &b_lds[(i * 256 + wave * 64) * 8]);
    }
    __syncthreads();
#pragma unroll
    for (int kk = 0; kk < 2; ++kk) {
      bf16x8 af[MR], bfr[NR];
#pragma unroll
      for (int m = 0; m < MR; ++m) {
        int row = wr * (MR * 16) + m * 16 + l15;
        af[m] = ld16(&a_lds[row * BK + kk * 32 + lg * 8]);
      }
#pragma unroll
      for (int n = 0; n < NR; ++n) {
        int row = wc * HBN + n * 16 + l15;
        bfr[n] = ld16(&b_lds[row * BK + kk * 32 + lg * 8]);
      }
#pragma unroll
      for (int m = 0; m < MR; ++m)
#pragma unroll
        for (int n = 0; n < NR; ++n)
          acc[m][n] = __builtin_amdgcn_mfma_f32_16x16x32_bf16(af[m], bfr[n], acc[m][n], 0, 0, 0);
    }
    __syncthreads();
  }

  // epilogue: C row = (lane>>4)*4 + j, col = lane&15 within each 16x16 tile
  if constexpr (MODE == 0) {
    const int base_col = n0 + wc * HBN;
    const int s = n0 / Dc;                 // uniform per block (96 | 768)
    if (s == 2) {
      // V -> [bh][d][L]: pack 4 consecutive tokens (j) per store
#pragma unroll
      for (int m = 0; m < 4; ++m) {
        int lq = m0 + wr * 64 + m * 16 + lg * 4;
        int b = lq >> 11, lql = lq & 2047;
#pragma unroll
        for (int n = 0; n < 3; ++n) {
          int cbase = base_col + n * 16;
          int h = (cbase % Dc) >> 6;
          int d = (cbase & 63) + l15;
          float bv = bias[cbase + l15];
          ushort4 o;
#pragma unroll
          for (int j = 0; j < 4; ++j)
            ((unsigned short*)&o)[j] = f2bf(acc[m][n][j] + bv);
          *reinterpret_cast<ushort4*>(
              vtb + ((size_t)(b * Hc + h) * HDc + d) * Lc + lql) = o;
        }
      }
    } else {
      // Q/K -> [bh][L][64]: per-wave LDS patch (16 x 48), then 16B vector stores
      unsigned short* dst = (s == 0) ? qb : kb;
      const float sc = (s == 0) ? (ATT_SCALE * LOG2E) : 1.0f;
#pragma unroll
      for (int m = 0; m < 4; ++m) {
#pragma unroll
        for (int n = 0; n < 3; ++n) {
          float bv = bias[base_col + n * 16 + l15];
#pragma unroll
          for (int j = 0; j < 4; ++j)
            qk_patch[wave][lg * 4 + j][n * 16 + l15] =
                f2bf((acc[m][n][j] + bv) * sc);
        }
        // 16 rows x 6 chunks of 16B = 96 tasks; each chunk lies within one head
#pragma unroll
        for (int i = 0; i < 2; ++i) {
          int task = i * 64 + lane;
          if (task < 96) {
            int r = task / 6, ch = task - r * 6;
            int gcol = base_col + ch * 8;
            int h = (gcol % Dc) >> 6;
            int d0 = gcol & 63;
            int lq = m0 + wr * 64 + m * 16 + r;
            int b = lq >> 11, lql = lq & 2047;
            u32x4 v = *reinterpret_cast<const u32x4*>(&qk_patch[wave][r][ch * 8]);
            *reinterpret_cast<u32x4*>(
                dst + ((size_t)(b * Hc + h) * Lc + lql) * HDc + d0) = v;
          }
        }
      }
    }
  } else {
#pragma unroll
    for (int m = 0; m < MR; ++m) {
      int row_base = m0 + wr * (MR * 16) + m * 16 + lg * 4;
#pragma unroll
      for (int n = 0; n < NR; ++n) {
        int col = n0 + wc * HBN + n * 16 + l15;
        float bv = bias[col];
#pragma unroll
        for (int j = 0; j < 4; ++j)
          Y[(size_t)(row_base + j) * Dc + col] = acc[m][n][j] + bv;
      }
    }
  }
}

// ---------------- flash attention v5s: R5 kernel + entry stagger (null but harmless) ----
// R20: stagger tested in isolation = NULL (46.2-46.7us, counters identical to R5) ->
// phase-lock theory falsified; the ~46.5us wall is the genuine multi-pipe operating
// point of this structure. attn DECLARED AT PRACTICAL FLOOR after 9 variants (46.2-61):
// R1 coalesced staging (69->47), then all of {counted-vmcnt dbuf/tbuf, cross-iter T15,
// x2 unroll, q-doubling, stagger} neutral-or-worse. FROZEN byte-for-byte.
__global__ __launch_bounds__(256) void attn_kernel(
    const unsigned short* __restrict__ qb,   // [BH][L][64], pre-scaled by SCALE*LOG2E
    const unsigned short* __restrict__ kb,   // [BH][L][64]
    const unsigned short* __restrict__ vtb,  // [BH][64][L] transposed
    const float* __restrict__ mb,            // [B][L]: 0 / -1e30
    const int* __restrict__ mflag,           // [B][L/64] any-masked flag
    unsigned short* __restrict__ aout) {     // [B][L][768]
  __shared__ alignas(16) unsigned short k_lds[4][4096];  // K ring-4, 8KB tiles, swizzled
  __shared__ alignas(16) unsigned short v_lds[2][4096];  // V ring-2
  __shared__ float l_lds[2][32];
  const int tid = threadIdx.x;
  const int lane = tid & 63;
  const int l31 = lane & 31;
  const int hi = lane >> 5;
  const int wave = tid >> 6;                 // 0..3
  const int ws = wave & 1;                   // q sub-tile (32 rows)
  const int g = wave >> 1;                   // kv sub-half of the 64-kv tile
  // XCD-clustered work assignment (768 = 8 XCD x 3 bh x 32 qblocks)
  const int f = blockIdx.x;
  const int loc = f >> 3;                    // 0..95
  const int bh = (f & 7) * 3 + (loc >> 5);
  const int b = bh / Hc, h = bh % Hc;
  const int q0 = (loc & 31) * 64 + ws * 32;

  // ---- R20: entry phase-stagger (measured null; kept — zero cost, best-measured build) ----
  {
    const int ph = f % 3;
    if (ph == 1) { asm volatile("s_sleep 8\n\ts_sleep 8" ::: "memory"); }
    else if (ph == 2) { asm volatile("s_sleep 8\n\ts_sleep 8\n\ts_sleep 8\n\ts_sleep 8" ::: "memory"); }
  }

  const unsigned short* Kbh = kb + (size_t)bh * Lc * HDc;
  const unsigned short* Vbh = vtb + (size_t)bh * HDc * Lc;
  const float* mbb = mb + b * Lc + hi * 4;
  const int* mfp = mflag + b * (Lc / 64);

  // mask-tile flags -> one 32-bit mask (keeps the main loop free of vector loads)
  unsigned long long mbits;
  {
    int mv = (lane < 32) ? mfp[lane] : 0;
    mbits = __ballot(mv != 0);
  }

  // Q as B-operand: lane holds Q[q0+l31][c*16 + hi*8 + j]
  bf16x8 qf[4];
  {
    const unsigned short* Qp = qb + ((size_t)bh * Lc + q0 + l31) * HDc + hi * 8;
#pragma unroll
    for (int c = 0; c < 4; ++c) qf[c] = ld16(Qp + c * 16);
  }

  // all-ones A-frag for MFMA row-sums
  bf16x8 onesf;
  {
    u32x4 ow = {0x3F803F80u, 0x3F803F80u, 0x3F803F80u, 0x3F803F80u};
    onesf = __builtin_bit_cast(bf16x8, ow);
  }

  f32x16 accO[2] = {};   // O^T[d][q]: d = dt*32 + (reg&3)+8*(reg>>2)+4*hi, q = q0+l31
  f32x16 accL = {};      // all rows = running sum over this wave's kv rows, col = q

  // staging: wave w owns chunks j={2w,2w+1} = 8 full rows each, inverse-swizzled cols.
  const int j0 = wave * 2, j1 = j0 + 1;
  const int r80 = j0 * 8 + (lane >> 3), r81 = r80 + 8;
  const int csw0 = (((lane & 7) ^ (lane >> 3) ^ (j0 & 3))) << 3;
  const int csw1 = (((lane & 7) ^ (lane >> 3) ^ (j1 & 3))) << 3;
  const unsigned short* kp0 = Kbh + (size_t)r80 * HDc + csw0;
  const unsigned short* kp1 = Kbh + (size_t)r81 * HDc + csw1;
  const unsigned short* vp0 = Vbh + (size_t)r80 * Lc + csw0;
  const unsigned short* vp1 = Vbh + (size_t)r81 * Lc + csw1;

#define STAGEK(buf)                               \
  {                                               \
    gload16(kp0, &k_lds[buf][j0 * 512]);          \
    gload16(kp1, &k_lds[buf][j1 * 512]);          \
    kp0 += 64 * HDc; kp1 += 64 * HDc;             \
  }
#define STAGEV(buf)                               \
  {                                               \
    gload16(vp0, &v_lds[buf][j0 * 512]);          \
    gload16(vp1, &v_lds[buf][j1 * 512]);          \
    vp0 += 64; vp1 += 64;                         \
  }

  const int swz = ((l31 & 7) ^ (l31 >> 3)) << 3;   // read-side XOR (row bits 0..4)
  const int krow = (g * 32 + l31) * 64;            // this wave's K row base (shorts)

  // ---- prologue: K0,K1,V0 landed; K2,V1 in flight; S = QK(tile0) ----
  STAGEK(0) STAGEK(1) STAGEV(0)
  asm volatile("s_waitcnt vmcnt(0)" ::: "memory");
  __builtin_amdgcn_s_barrier();
  f32x16 s = {};
#pragma unroll
  for (int c = 0; c < 4; ++c) {
    int ch = (((c * 2 + hi) << 3) ^ swz);
    s = __builtin_amdgcn_mfma_f32_32x32x16_bf16(
        ld16(&k_lds[0][0] + krow + ch), qf[c], s, 0, 0, 0);
  }
  STAGEK(2) STAGEV(1)

  constexpr int NSTEP = Lc / 64;   // 32
  for (int t = 0; t < NSTEP; ++t) {
    if (t + 3 < NSTEP) STAGEK((t + 3) & 3)

    // ---- S' = QK(t+1): independent MFMA chain, overlaps softmax(t) below ----
    f32x16 s2 = {};
    if (t + 1 < NSTEP) {
      const unsigned short* kl = &k_lds[(t + 1) & 3][0];
      __builtin_amdgcn_s_setprio(1);
#pragma unroll
      for (int c = 0; c < 4; ++c) {
        int ch = (((c * 2 + hi) << 3) ^ swz);
        s2 = __builtin_amdgcn_mfma_f32_32x32x16_bf16(
            ld16(kl + krow + ch), qf[c], s2, 0, 0, 0);
      }
      __builtin_amdgcn_s_setprio(0);
    }

    // ---- softmax(t) on s: mask, exp2, pack (no sum chain — sums via MFMA) ----
    if ((mbits >> t) & 1ull) {
      const int kvt = t * 64 + g * 32;
#pragma unroll
      for (int gg = 0; gg < 4; ++gg) {
        float4 m0v = *reinterpret_cast<const float4*>(mbb + kvt + gg * 8);
        s[gg * 4 + 0] += m0v.x; s[gg * 4 + 1] += m0v.y;
        s[gg * 4 + 2] += m0v.z; s[gg * 4 + 3] += m0v.w;
      }
    }
#pragma unroll
    for (int i = 0; i < 16; ++i) s[i] = __builtin_amdgcn_exp2f(s[i]);
    bf16x8 pf[2];
#pragma unroll
    for (int c = 0; c < 2; ++c) {
      const int o = c * 8;
      unsigned pk01 = cvtpk(s[o + 0], s[o + 1]);
      unsigned pk23 = cvtpk(s[o + 2], s[o + 3]);
      unsigned pk45 = cvtpk(s[o + 4], s[o + 5]);
      unsigned pk67 = cvtpk(s[o + 6], s[o + 7]);
      asm("v_permlane32_swap_b32 %0, %1" : "+v"(pk01), "+v"(pk45));
      asm("v_permlane32_swap_b32 %0, %1" : "+v"(pk23), "+v"(pk67));
      u32x4 w = {pk01, pk23, pk45, pk67};
      pf[c] = __builtin_bit_cast(bf16x8, w);
    }
    // ---- row sums on the MFMA pipe ----
    accL = __builtin_amdgcn_mfma_f32_32x32x16_bf16(onesf, pf[0], accL, 0, 0, 0);
    accL = __builtin_amdgcn_mfma_f32_32x32x16_bf16(onesf, pf[1], accL, 0, 0, 0);
    // ---- O^T += V^T P^T over this wave's 32 kv rows ----
    {
      const unsigned short* vl = &v_lds[t & 1][0];
      __builtin_amdgcn_s_setprio(1);
#pragma unroll
      for (int dt = 0; dt < 2; ++dt) {
#pragma unroll
        for (int c = 0; c < 2; ++c) {
          int ch = (((g * 4 + c * 2 + hi) << 3) ^ swz);
          accO[dt] = __builtin_amdgcn_mfma_f32_32x32x16_bf16(
              ld16(vl + (dt * 32 + l31) * 64 + ch), pf[c], accO[dt], 0, 0, 0);
        }
      }
      __builtin_amdgcn_s_setprio(0);
    }
    // ---- end of iter: counted drain of {K(t+2), V(t+1)}; K(t+3) stays in flight ----
    if (t < NSTEP - 3) {
      asm volatile("s_waitcnt vmcnt(2)" ::: "memory");
    } else {
      asm volatile("s_waitcnt vmcnt(0)" ::: "memory");
    }
    __builtin_amdgcn_s_barrier();
    __builtin_amdgcn_sched_barrier(0);
    if (t + 2 < NSTEP) STAGEV((t) & 1)   // V(t+2) -> vbuf[t&1], just freed by PV(t)
    s = s2;
  }

  // ---- merge kv sub-halves: g=1 publishes into dead k_lds, g=0 combines & writes ----
  __syncthreads();
  const float l_run = accL[0];
  float* mO = (float*)&k_lds[0][0];   // [ws][32][64] floats = 16KB, lane-major
  if (g == 1) {
#pragma unroll
    for (int dt = 0; dt < 2; ++dt)
#pragma unroll
      for (int i = 0; i < 16; ++i)
        mO[(ws * 32 + dt * 16 + i) * 64 + lane] = accO[dt][i];
    if (hi == 0) l_lds[ws][l31] = l_run;
  }
  __syncthreads();
  if (g == 0) {
    float rl = 1.0f / (l_run + l_lds[ws][l31]);
    const int q = q0 + l31;
    unsigned short* op = aout + ((size_t)(b * Lc + q)) * Dc + h * HDc;
#pragma unroll
    for (int dt = 0; dt < 2; ++dt)
#pragma unroll
      for (int gg = 0; gg < 4; ++gg) {
        ushort4 o;
#pragma unroll
        for (int j = 0; j < 4; ++j) {
          int i = gg * 4 + j;
          float v = (accO[dt][i] + mO[(ws * 32 + dt * 16 + i) * 64 + lane]) * rl;
          ((unsigned short*)&o)[j] = f2bf(v);
        }
        *reinterpret_cast<ushort4*>(op + dt * 32 + gg * 8 + hi * 4) = o;
      }
  }
}

// ---------------- launch ----------------
extern "C" void kernel_launch(void* const* d_in, const int* in_sizes, int n_in,
                              void* d_out, int out_size, void* d_ws, size_t ws_size,
                              hipStream_t stream) {
  const float* x    = (const float*)d_in[0];
  const int*   mask = (const int*)d_in[1];
  const float* Wqkv = (const float*)d_in[2];
  const float* bqkv = (const float*)d_in[3];
  const float* Wout = (const float*)d_in[4];
  const float* bout = (const float*)d_in[5];
  float* out = (float*)d_out;

  constexpr size_t NX   = (size_t)NTOK * Dc;      // 3145728
  constexpr size_t NWQ  = (size_t)QKVN * Dc;      // 1769472
  constexpr size_t NWO  = (size_t)Dc * Dc;        // 589824
  unsigned short* w = (unsigned short*)d_ws;
  unsigned short* xb    = w;            w += NX;
  unsigned short* wqkvb = w;            w += NWQ;
  unsigned short* woutb = w;            w += NWO;
  unsigned short* qbuf  = w;            w += NX;
  unsigned short* kbuf  = w;            w += NX;
  unsigned short* vtb   = w;            w += NX;
  unsigned short* aoutb = w;            w += NX;
  float* mbf = (float*)w;               w += 2 * NTOK;
  int* mflag = (int*)w;

  // fused converts + mask aux (one launch instead of four)
  prep_kernel<<<5392, 256, 0, stream>>>(x, Wqkv, Wout, mask, xb, wqkvb, woutb, mbf, mflag);

  // QKV projection: M=4096, N=2304, K=768 — grid 32x24 = 768 = 3 blocks/CU exact
  gemm_bt<0><<<(NTOK / 128) * (QKVN / 96), 256, 0, stream>>>(
      xb, wqkvb, bqkv, qbuf, kbuf, vtb, nullptr, NTOK, QKVN, Dc);

  // attention: 768 blocks x 256 threads (8 XCD x 3 bh x 32 qblocks; 2 q-subtiles x 2 kv-subhalves)
  attn_kernel<<<dim3(768), 256, 0, stream>>>(qbuf, kbuf, vtb, mbf, mflag, aoutb);

  // output projection: M=4096, N=768, K=768 — R21: grid 64x12 = 768 = 3 blocks/CU exact,
  // 16 MFMA : 8 ds_read per wave-K-tile (was 12:10 at BM64/BN96, 2/CU)
  gemm_bt<1><<<(NTOK / 64) * (Dc / 64), 256, 0, stream>>>(
      aoutb, woutb, bout, nullptr, nullptr, nullptr, out, NTOK, Dc, Dc);
}